// Round 13
// baseline (249.394 us; speedup 1.0000x reference)
//
#include <hip/hip_runtime.h>
#include <math.h>

typedef __attribute__((ext_vector_type(8))) short bf16x8;
typedef __attribute__((ext_vector_type(8))) unsigned short u16x8;
typedef __attribute__((ext_vector_type(4))) unsigned short u16x4;
typedef __attribute__((ext_vector_type(4))) float f32x4;
typedef unsigned short u16;

__device__ __forceinline__ u16 f2bf(float f) {
  unsigned u = __builtin_bit_cast(unsigned, f);
  return (u16)((u + 0x7FFFu + ((u >> 16) & 1u)) >> 16);
}

__device__ __forceinline__ void gload16(const u16* g, u16* l) {
  __builtin_amdgcn_global_load_lds((const __attribute__((address_space(1))) void*)g,
                                   (__attribute__((address_space(3))) void*)l, 16, 0, 0);
}

__device__ __forceinline__ void sbar() {
  __builtin_amdgcn_sched_barrier(0);
  __builtin_amdgcn_s_barrier();
  __builtin_amdgcn_sched_barrier(0);
}

#define VMWAIT(n) asm volatile("s_waitcnt vmcnt(" #n ")" ::: "memory")
#define MFMA16(a, b, c) __builtin_amdgcn_mfma_f32_16x16x32_bf16((a), (b), (c), 0, 0, 0)

__device__ __forceinline__ float decay_of(float d) {
  return 1e-12f + 0.5f + 0.5f / (1.0f + expf(-d));
}

// ---------------- prep: 3x f32 -> bf16 (w1, w2, audio fused) ----------------
__global__ __launch_bounds__(256) void cvt3_kernel(const float* __restrict__ a,
                                                   const float* __restrict__ b,
                                                   const float* __restrict__ c,
                                                   u16* __restrict__ out) {
  const int i = blockIdx.x * 256 + threadIdx.x;   // i < 3 * 1048576 (float4 units)
  const float* src;
  int j = i;
  if (i < 1048576) { src = a; }
  else if (i < 2097152) { src = b; j = i - 1048576; }
  else { src = c; j = i - 2097152; }
  const float4 v = ((const float4*)src)[j];
  u16x4 o = { f2bf(v.x), f2bf(v.y), f2bf(v.z), f2bf(v.w) };
  ((u16x4*)out)[i] = o;
}

// ---------------- prep: relu(cp) transposed to [t][c] bf16 ----------------
__global__ __launch_bounds__(256) void relu_t_kernel(const float* __restrict__ cp,
                                                     u16* __restrict__ x0t) {
  const int cb = blockIdx.x & 31;
  const int tb = blockIdx.x >> 5;
  __shared__ __attribute__((aligned(16))) float tile[64][65];
  const int tid = threadIdx.x;
  const int r0 = tid >> 4, i4 = (tid & 15) * 4;
  #pragma unroll
  for (int rr = 0; rr < 64; rr += 16) {
    const float4 v = *(const float4*)(cp + (size_t)(cb * 64 + r0 + rr) * 4096 + tb * 64 + i4);
    tile[r0 + rr][i4 + 0] = fmaxf(v.x, 0.f);
    tile[r0 + rr][i4 + 1] = fmaxf(v.y, 0.f);
    tile[r0 + rr][i4 + 2] = fmaxf(v.z, 0.f);
    tile[r0 + rr][i4 + 3] = fmaxf(v.w, 0.f);
  }
  __syncthreads();
  #pragma unroll
  for (int it = 0; it < 2; ++it) {
    const int chunk = it * 256 + tid;
    const int i = chunk >> 3, rp = (chunk & 7) * 8;
    u16x8 o;
    #pragma unroll
    for (int q = 0; q < 8; ++q) o[q] = f2bf(tile[rp + q][i]);
    *(u16x8*)(x0t + (size_t)(tb * 64 + i) * 2048 + cb * 64 + rp) = o;
  }
}

// ---------------- IIR blocked scan ----------------
__global__ __launch_bounds__(128) void iir_partial_kernel(const float* __restrict__ x,
                                                          const float* __restrict__ decays,
                                                          float* __restrict__ L) {
  const int tid = threadIdx.x;
  const int cb = blockIdx.x & 15;
  const int ck = blockIdx.x >> 4;
  const int c0 = cb * 128, t0 = ck * 64;
  __shared__ __attribute__((aligned(16))) float xs[128][65];
  const float dd = decay_of(decays[c0 + tid]);
  #pragma unroll
  for (int it = 0; it < 16; ++it) {
    const int idx = it * 128 + tid;
    const int r = idx >> 4, iv = (idx & 15) * 4;
    const float4 v = *(const float4*)(x + (size_t)(c0 + r) * 4096 + t0 + iv);
    xs[r][iv + 0] = v.x; xs[r][iv + 1] = v.y; xs[r][iv + 2] = v.z; xs[r][iv + 3] = v.w;
  }
  __syncthreads();
  float yv = 0.0f;
  #pragma unroll
  for (int i = 0; i < 64; ++i) yv = dd * (xs[tid][i] + yv);
  L[ck * 2048 + c0 + tid] = yv;
}

__global__ __launch_bounds__(128) void iir_carry_kernel(const float* __restrict__ L,
                                                        const float* __restrict__ decays,
                                                        float* __restrict__ Cin) {
  const int c = blockIdx.x * 128 + threadIdx.x;
  const float dd = decay_of(decays[c]);
  float A = dd;
  #pragma unroll
  for (int p = 0; p < 6; ++p) A = A * A;   // dd^64
  float carry = 0.0f;
  for (int j = 0; j < 64; ++j) {
    Cin[j * 2048 + c] = carry;
    carry = L[j * 2048 + c] + A * carry;
  }
}

__global__ __launch_bounds__(128) void iir_apply_kernel(const float* __restrict__ x,
                                                        const float* __restrict__ decays,
                                                        const float* __restrict__ Cin,
                                                        u16* __restrict__ yT) {
  const int tid = threadIdx.x;
  const int cb = blockIdx.x & 15;
  const int ck = blockIdx.x >> 4;
  const int c0 = cb * 128, t0 = ck * 64;
  __shared__ __attribute__((aligned(16))) float xs[128][65];
  __shared__ __attribute__((aligned(16))) u16 ys[64][136];
  const float dd = decay_of(decays[c0 + tid]);
  const float carry = Cin[ck * 2048 + c0 + tid];
  #pragma unroll
  for (int it = 0; it < 16; ++it) {
    const int idx = it * 128 + tid;
    const int r = idx >> 4, iv = (idx & 15) * 4;
    const float4 v = *(const float4*)(x + (size_t)(c0 + r) * 4096 + t0 + iv);
    xs[r][iv + 0] = v.x; xs[r][iv + 1] = v.y; xs[r][iv + 2] = v.z; xs[r][iv + 3] = v.w;
  }
  __syncthreads();
  float yv = carry;
  #pragma unroll
  for (int i = 0; i < 64; ++i) {
    yv = dd * (xs[tid][i] + yv);
    ys[i][tid] = f2bf(yv);
  }
  __syncthreads();
  #pragma unroll
  for (int it = 0; it < 8; ++it) {
    const int chunk = it * 128 + tid;
    const int i = chunk >> 4, cpv = (chunk & 15) * 8;
    u16x8 v = *(const u16x8*)&ys[i][cpv];
    *(u16x8*)(yT + (size_t)(t0 + i) * 2048 + c0 + cpv) = v;
  }
}

// ---------------- GEMM: 128x256 tile, BK=64, triple-buffer, dual-barrier phases ----------------
// C[M][N] = A[M][K] @ Bt[N][K]^T. 512 thr = 8 waves (2M x 4N), per-wave 64x64.
// m201-template phase: {stage gloads || ds_read 8 frags -> barrier -> setprio(1)
// -> 16 MFMA (pure reg) -> setprio(0) -> barrier}. 2 phases per K-tile; vmcnt(6)
// gate once per K-tile (2-tile prefetch depth, never drains in steady state).
// Grid 256 = 1 block/CU, all CUs active. 144 KB LDS.
template <int MODE>
__global__ __launch_bounds__(512, 1) void gemm_tp_kernel(
    const u16* __restrict__ A, const u16* __restrict__ Bt, float* __restrict__ C,
    int N, int K, int xlogn,
    const float* __restrict__ orig, const float* __restrict__ gains,
    u16* __restrict__ CbT) {
  __shared__ __attribute__((aligned(16))) u16 Asb[3][128 * 64];  // 48 KB
  __shared__ __attribute__((aligned(16))) u16 Bsb[3][256 * 64];  // 96 KB
  const int tid = threadIdx.x;
  const int l = tid & 63, w = tid >> 6;
  // XCD-rect swizzle over 256 blocks: rect = 8bm x 4bn per XCD.
  const int xc = blockIdx.x & 7, rblk = blockIdx.x >> 3;   // rblk in [0,32)
  const int xn = xc & ((1 << xlogn) - 1), xm = xc >> xlogn;
  const int bm = xm * 8 + (rblk >> 2);
  const int bn = xn * 4 + (rblk & 3);
  const int nt = K >> 6;   // 32

  // staging: unit u of wave w covers rows (u*8+w)*8 + (l>>3); swizzled chunk.
  // LDS[r][c] = G[r][c ^ (r&7)] (involution; reads apply same XOR).
  const int cs = (l & 7) ^ (l >> 3);
  const int rsub = l >> 3;
  const u16* aS[2]; const u16* bS[4]; int aO[2], bO[4];
  #pragma unroll
  for (int u = 0; u < 2; ++u) {
    const int rg = (u * 8 + w) * 8 + rsub;
    aS[u] = A + (size_t)(bm * 128 + rg) * K + cs * 8;
    aO[u] = (u * 8 + w) * 512;
  }
  #pragma unroll
  for (int u = 0; u < 4; ++u) {
    const int rg = (u * 8 + w) * 8 + rsub;
    bS[u] = Bt + (size_t)(bn * 256 + rg) * K + cs * 8;
    bO[u] = (u * 8 + w) * 512;
  }

#define STAGE6(bufA, bufB, tt) do {                                        \
    const long so_ = (long)(tt) * 64;                                      \
    gload16(aS[0] + so_, (bufA) + aO[0]); gload16(aS[1] + so_, (bufA) + aO[1]); \
    gload16(bS[0] + so_, (bufB) + bO[0]); gload16(bS[1] + so_, (bufB) + bO[1]); \
    gload16(bS[2] + so_, (bufB) + bO[2]); gload16(bS[3] + so_, (bufB) + bO[3]); \
  } while (0)

  const int wr = w >> 2, wc = w & 3;
  const int rA0 = wr * 64 + (l & 15);
  const int rB0 = wc * 64 + (l & 15);
  const int jk0 = (l >> 4) ^ (l & 7);        // swizzled chunk, k-half 0
  const int jk1 = ((l >> 4) + 4) ^ (l & 7);  // swizzled chunk, k-half 1

  f32x4 acc[4][4];
  #pragma unroll
  for (int i = 0; i < 4; ++i)
    #pragma unroll
    for (int j = 0; j < 4; ++j) acc[i][j] = (f32x4){0.f, 0.f, 0.f, 0.f};

  // prologue: stage tiles 0 and 1 (6 loads each)
  STAGE6((u16*)Asb[0], (u16*)Bsb[0], 0);
  STAGE6((u16*)Asb[1], (u16*)Bsb[1], 1);
  VMWAIT(6);                 // tile 0 landed; tile 1's 6 in flight
  sbar();

  for (int t = 0; t < nt; ++t) {
    const int cur = t % 3;
    const int nxt = (t + 2) % 3;
    const u16* Ac = (const u16*)Asb[0] + cur * 8192;
    const u16* Bc = (const u16*)Bsb[0] + cur * 16384;
    u16* An = (u16*)Asb[0] + nxt * 8192;
    u16* Bn = (u16*)Bsb[0] + nxt * 16384;
    const bool st = (t + 2) < nt;
    const long so = (long)(t + 2) * 64;

    // ---- phase 0: stage A(t+2)+B0(t+2); read jk0 frags; barrier; 16 MFMA; barrier ----
    if (st) { gload16(aS[0] + so, An + aO[0]); gload16(aS[1] + so, An + aO[1]);
              gload16(bS[0] + so, Bn + bO[0]); }
    {
      bf16x8 a0[4], b0[4];
      #pragma unroll
      for (int mi = 0; mi < 4; ++mi)
        a0[mi] = *(const bf16x8*)(Ac + (rA0 + mi * 16) * 64 + jk0 * 8);
      #pragma unroll
      for (int ni = 0; ni < 4; ++ni)
        b0[ni] = *(const bf16x8*)(Bc + (rB0 + ni * 16) * 64 + jk0 * 8);
      sbar();
      __builtin_amdgcn_s_setprio(1);
      #pragma unroll
      for (int mi = 0; mi < 4; ++mi)
        #pragma unroll
        for (int ni = 0; ni < 4; ++ni)
          acc[mi][ni] = MFMA16(a0[mi], b0[ni], acc[mi][ni]);
      __builtin_amdgcn_s_setprio(0);
      sbar();
    }

    // ---- phase 1: stage B123(t+2); read jk1 frags; barrier; 16 MFMA; gate; barrier ----
    if (st) { gload16(bS[1] + so, Bn + bO[1]); gload16(bS[2] + so, Bn + bO[2]);
              gload16(bS[3] + so, Bn + bO[3]); }
    {
      bf16x8 a1[4], b1[4];
      #pragma unroll
      for (int mi = 0; mi < 4; ++mi)
        a1[mi] = *(const bf16x8*)(Ac + (rA0 + mi * 16) * 64 + jk1 * 8);
      #pragma unroll
      for (int ni = 0; ni < 4; ++ni)
        b1[ni] = *(const bf16x8*)(Bc + (rB0 + ni * 16) * 64 + jk1 * 8);
      sbar();
      __builtin_amdgcn_s_setprio(1);
      #pragma unroll
      for (int mi = 0; mi < 4; ++mi)
        #pragma unroll
        for (int ni = 0; ni < 4; ++ni)
          acc[mi][ni] = MFMA16(a1[mi], b1[ni], acc[mi][ni]);
      __builtin_amdgcn_s_setprio(0);
      // gate: tile t+1 landed (its 6 loads issued during tile t-1); t+2's stay in flight
      if (st) { VMWAIT(6); } else { VMWAIT(0); }
      sbar();
    }
  }
#undef STAGE6

  // ---------------- epilogue ----------------
  const int rb = bm * 128 + wr * 64 + ((l >> 4) * 4);
  const int cb = bn * 256 + wc * 64 + (l & 15);
  #pragma unroll
  for (int mi = 0; mi < 4; ++mi) {
    const int row0 = rb + mi * 16;
    float gv[4] = {0.f, 0.f, 0.f, 0.f};
    if (MODE == 1) {
      #pragma unroll
      for (int j = 0; j < 4; ++j) gv[j] = 5.0f / (1.0f + expf(-gains[row0 + j]));
    }
    #pragma unroll
    for (int ni = 0; ni < 4; ++ni) {
      const int col = cb + ni * 16;
      f32x4 v = acc[mi][ni];
      if (MODE == 1) {
        float cpv[4];
        #pragma unroll
        for (int j = 0; j < 4; ++j) {
          float t = v[j] + orig[(size_t)(row0 + j) * N + col];
          cpv[j] = tanhf(t * gv[j]);
          C[(size_t)(row0 + j) * N + col] = cpv[j];
        }
        u16x4 o = { f2bf(cpv[0]), f2bf(cpv[1]), f2bf(cpv[2]), f2bf(cpv[3]) };
        *(u16x4*)(CbT + (size_t)col * 2048 + row0) = o;
      } else {
        #pragma unroll
        for (int j = 0; j < 4; ++j)
          C[(size_t)(row0 + j) * N + col] = v[j];
      }
    }
  }
}

extern "C" void kernel_launch(void* const* d_in, const int* in_sizes, int n_in,
                              void* d_out, int out_size, void* d_ws, size_t ws_size,
                              hipStream_t stream) {
  const float* cp     = (const float*)d_in[0];
  const float* w1     = (const float*)d_in[1];
  const float* w2     = (const float*)d_in[2];
  const float* audio  = (const float*)d_in[3];
  const float* decays = (const float*)d_in[4];
  const float* gains  = (const float*)d_in[5];

  float* out0 = (float*)d_out;                   // audio_out: [t][w] flat
  float* out1 = out0 + (size_t)2048 * 4096;      // cp_out: [c][t]

  char* ws = (char*)d_ws;
  u16*   w1b    = (u16*)(ws);                    //  8 MB
  u16*   w2b    = (u16*)(ws + 8388608);          //  8 MB
  u16*   audiob = (u16*)(ws + 16777216);         //  8 MB
  float* orig   = (float*)(ws + 25165824);       // 32 MB
  u16*   yT     = (u16*)(ws + 58720256);         // 16 MB
  u16*   x0t    = (u16*)(ws + 75497472);         // 16 MB
  u16*   cpbT   = x0t;                           // reuse after GEMM1
  float* Lbuf   = (float*)(ws + 75497472);       // overlap (dead between GEMM1/GEMM2)
  float* Cin    = (float*)(ws + 75497472 + 524288);

  cvt3_kernel<<<12288, 256, 0, stream>>>(w1, w2, audio, w1b);
  relu_t_kernel<<<2048, 256, 0, stream>>>(cp, x0t);

  // x = w1 @ relu(cp) -> orig[2048][4096]   (bm 16 x bn 16; XCD rect 8x4, xlogn=2)
  gemm_tp_kernel<0><<<256, 512, 0, stream>>>(w1b, x0t, orig, 4096, 2048, 2,
                                             nullptr, nullptr, nullptr);
  // y = IIR(orig) -> yT[4096][2048] bf16
  iir_partial_kernel<<<1024, 128, 0, stream>>>(orig, decays, Lbuf);
  iir_carry_kernel<<<16, 128, 0, stream>>>(Lbuf, decays, Cin);
  iir_apply_kernel<<<1024, 128, 0, stream>>>(orig, decays, Cin, yT);
  // x2 = w2 @ y + orig; cp_out = tanh(x2*g) -> out1 f32, cpbT[t][c] bf16
  gemm_tp_kernel<1><<<256, 512, 0, stream>>>(w2b, yT, out1, 4096, 2048, 2,
                                             orig, gains, cpbT);
  // audio_out[t][w] = cpbT @ audiob^T   (bm 32 x bn 8; XCD rect 8x4, xlogn=1)
  gemm_tp_kernel<0><<<256, 512, 0, stream>>>(cpbT, audiob, out0, 2048, 2048, 1,
                                             nullptr, nullptr, nullptr);
}

// Round 14
// 167.480 us; speedup vs baseline: 1.4891x; 1.4891x over previous
//
#include <hip/hip_runtime.h>
#include <math.h>

typedef __attribute__((ext_vector_type(8))) short bf16x8;
typedef __attribute__((ext_vector_type(8))) unsigned short u16x8;
typedef __attribute__((ext_vector_type(4))) unsigned short u16x4;
typedef __attribute__((ext_vector_type(4))) float f32x4;
typedef unsigned short u16;

__device__ __forceinline__ u16 f2bf(float f) {
  unsigned u = __builtin_bit_cast(unsigned, f);
  return (u16)((u + 0x7FFFu + ((u >> 16) & 1u)) >> 16);
}

__device__ __forceinline__ void gload16(const u16* g, u16* l) {
  __builtin_amdgcn_global_load_lds((const __attribute__((address_space(1))) void*)g,
                                   (__attribute__((address_space(3))) void*)l, 16, 0, 0);
}

__device__ __forceinline__ void sbar() {
  __builtin_amdgcn_sched_barrier(0);
  __builtin_amdgcn_s_barrier();
  __builtin_amdgcn_sched_barrier(0);
}

#define VMWAIT(n) asm volatile("s_waitcnt vmcnt(" #n ")" ::: "memory")
#define MFMA16(a, b, c) __builtin_amdgcn_mfma_f32_16x16x32_bf16((a), (b), (c), 0, 0, 0)

__device__ __forceinline__ float decay_of(float d) {
  return 1e-12f + 0.5f + 0.5f / (1.0f + expf(-d));
}

// ---------------- prep: 3x f32 -> bf16 (w1, w2, audio fused) ----------------
__global__ __launch_bounds__(256) void cvt3_kernel(const float* __restrict__ a,
                                                   const float* __restrict__ b,
                                                   const float* __restrict__ c,
                                                   u16* __restrict__ out) {
  const int i = blockIdx.x * 256 + threadIdx.x;   // i < 3 * 1048576 (float4 units)
  const float* src;
  int j = i;
  if (i < 1048576) { src = a; }
  else if (i < 2097152) { src = b; j = i - 1048576; }
  else { src = c; j = i - 2097152; }
  const float4 v = ((const float4*)src)[j];
  u16x4 o = { f2bf(v.x), f2bf(v.y), f2bf(v.z), f2bf(v.w) };
  ((u16x4*)out)[i] = o;
}

// ---------------- prep: relu(cp) transposed to [t][c] bf16 ----------------
__global__ __launch_bounds__(256) void relu_t_kernel(const float* __restrict__ cp,
                                                     u16* __restrict__ x0t) {
  const int cb = blockIdx.x & 31;
  const int tb = blockIdx.x >> 5;
  __shared__ __attribute__((aligned(16))) float tile[64][65];
  const int tid = threadIdx.x;
  const int r0 = tid >> 4, i4 = (tid & 15) * 4;
  #pragma unroll
  for (int rr = 0; rr < 64; rr += 16) {
    const float4 v = *(const float4*)(cp + (size_t)(cb * 64 + r0 + rr) * 4096 + tb * 64 + i4);
    tile[r0 + rr][i4 + 0] = fmaxf(v.x, 0.f);
    tile[r0 + rr][i4 + 1] = fmaxf(v.y, 0.f);
    tile[r0 + rr][i4 + 2] = fmaxf(v.z, 0.f);
    tile[r0 + rr][i4 + 3] = fmaxf(v.w, 0.f);
  }
  __syncthreads();
  #pragma unroll
  for (int it = 0; it < 2; ++it) {
    const int chunk = it * 256 + tid;
    const int i = chunk >> 3, rp = (chunk & 7) * 8;
    u16x8 o;
    #pragma unroll
    for (int q = 0; q < 8; ++q) o[q] = f2bf(tile[rp + q][i]);
    *(u16x8*)(x0t + (size_t)(tb * 64 + i) * 2048 + cb * 64 + rp) = o;
  }
}

// ---------------- IIR pass 2 (in-place): LC holds L in, Cin out ----------------
__global__ __launch_bounds__(128) void iir_carry_kernel(float* __restrict__ LC,
                                                        const float* __restrict__ decays) {
  const int c = blockIdx.x * 128 + threadIdx.x;
  const float dd = decay_of(decays[c]);
  float A = dd;
  #pragma unroll
  for (int p = 0; p < 6; ++p) A = A * A;   // dd^64
  float carry = 0.0f;
  for (int j = 0; j < 64; ++j) {
    const float Lj = LC[j * 2048 + c];
    LC[j * 2048 + c] = carry;              // Cin[j] = C_{j-1}
    carry = Lj + A * carry;                // C_j
  }
}

// ---------------- IIR pass 3: seeded local scan, write yT[t][c] bf16 ----------------
__global__ __launch_bounds__(128) void iir_apply_kernel(const float* __restrict__ x,
                                                        const float* __restrict__ decays,
                                                        const float* __restrict__ Cin,
                                                        u16* __restrict__ yT) {
  const int tid = threadIdx.x;
  const int cb = blockIdx.x & 15;
  const int ck = blockIdx.x >> 4;
  const int c0 = cb * 128, t0 = ck * 64;
  __shared__ __attribute__((aligned(16))) float xs[128][65];
  __shared__ __attribute__((aligned(16))) u16 ys[64][136];
  const float dd = decay_of(decays[c0 + tid]);
  const float carry = Cin[ck * 2048 + c0 + tid];
  #pragma unroll
  for (int it = 0; it < 16; ++it) {
    const int idx = it * 128 + tid;
    const int r = idx >> 4, iv = (idx & 15) * 4;
    const float4 v = *(const float4*)(x + (size_t)(c0 + r) * 4096 + t0 + iv);
    xs[r][iv + 0] = v.x; xs[r][iv + 1] = v.y; xs[r][iv + 2] = v.z; xs[r][iv + 3] = v.w;
  }
  __syncthreads();
  float yv = carry;
  #pragma unroll
  for (int i = 0; i < 64; ++i) {
    yv = dd * (xs[tid][i] + yv);
    ys[i][tid] = f2bf(yv);
  }
  __syncthreads();
  #pragma unroll
  for (int it = 0; it < 8; ++it) {
    const int chunk = it * 128 + tid;
    const int i = chunk >> 4, cpv = (chunk & 15) * 8;
    u16x8 v = *(const u16x8*)&ys[i][cpv];
    *(u16x8*)(yT + (size_t)(t0 + i) * 2048 + c0 + cpv) = v;
  }
}

// ---------------- GEMM helpers ----------------
__device__ __forceinline__ void read_frag(const u16* Ac, const u16* Bc,
                                          int rA0, int rB0, int jk,
                                          bf16x8 (&a)[4], bf16x8 (&b)[4]) {
  #pragma unroll
  for (int i = 0; i < 4; ++i)
    a[i] = *(const bf16x8*)(Ac + (rA0 + i * 16) * 64 + jk * 8);
  #pragma unroll
  for (int i = 0; i < 4; ++i)
    b[i] = *(const bf16x8*)(Bc + (rB0 + i * 16) * 64 + jk * 8);
}

__device__ __forceinline__ void mfma16x(const bf16x8 (&a)[4], const bf16x8 (&b)[4],
                                        f32x4 (&acc)[4][4]) {
  __builtin_amdgcn_s_setprio(1);
  #pragma unroll
  for (int mi = 0; mi < 4; ++mi)
    #pragma unroll
    for (int ni = 0; ni < 4; ++ni)
      acc[mi][ni] = MFMA16(a[mi], b[ni], acc[mi][ni]);
  __builtin_amdgcn_s_setprio(0);
}

// ---------------- GEMM: 128x128 tile, BK=64, double-buffer, pipelined, 2 blocks/CU ----------------
// C[M][N] = A[M][K] @ Bt[N][K]^T. 256 thr = 4 waves (2M x 2N), per-wave 64x64.
// MODE 0: plain store. MODE 1: fused orig-add+tanh epilogue (+bf16^T store).
// MODE 2: plain store + fused IIR chunk-local scan (stage tile in dead LDS,
//         per-(channel,64-frame-chunk) scan, write L[ck][c]).
template <int MODE>
__global__ __launch_bounds__(256, 2) void gemm_pl_kernel(
    const u16* __restrict__ A, const u16* __restrict__ Bt, float* __restrict__ C,
    int N, int K, int xlogn,
    const float* __restrict__ orig, const float* __restrict__ gains,
    u16* __restrict__ CbT,
    const float* __restrict__ decays, float* __restrict__ Lout) {
  // 66048 B: staging (2x16KB A + 2x16KB B) overlaid with 128x129 f32 C-stage.
  __shared__ __attribute__((aligned(16))) char smem[66048];
  u16* AsB = (u16*)smem;             // [2][8192]
  u16* BsB = (u16*)(smem + 32768);   // [2][8192]
  float* cst = (float*)smem;         // [128][129] (MODE 2 epilogue)
  const int tid = threadIdx.x;
  const int l = tid & 63, w = tid >> 6;
  const int xc = blockIdx.x & 7, rblk = blockIdx.x >> 3;
  const int xn = xc & ((1 << xlogn) - 1), xm = xc >> xlogn;
  const int bm = xm * 8 + (rblk >> 3);
  const int bn = xn * 8 + (rblk & 7);
  const int nt = K >> 6;   // 32

  // staging: LDS[r][c] = G[r][c ^ (r&7)] (involution; reads apply same XOR)
  const int cs = (l & 7) ^ (l >> 3);
  const int rsub = l >> 3;
  const u16* aS[4]; const u16* bS[4]; int tO[4];
  #pragma unroll
  for (int u = 0; u < 4; ++u) {
    const int rg = (u * 4 + w) * 8 + rsub;
    aS[u] = A  + (size_t)(bm * 128 + rg) * K + cs * 8;
    bS[u] = Bt + (size_t)(bn * 128 + rg) * K + cs * 8;
    tO[u] = (u * 4 + w) * 512;
  }

#define STAGE(bufA, bufB, tt) do {                                        \
    const long so_ = (long)(tt) * 64;                                     \
    gload16(aS[0] + so_, (bufA) + tO[0]); gload16(aS[1] + so_, (bufA) + tO[1]); \
    gload16(aS[2] + so_, (bufA) + tO[2]); gload16(aS[3] + so_, (bufA) + tO[3]); \
    gload16(bS[0] + so_, (bufB) + tO[0]); gload16(bS[1] + so_, (bufB) + tO[1]); \
    gload16(bS[2] + so_, (bufB) + tO[2]); gload16(bS[3] + so_, (bufB) + tO[3]); \
  } while (0)

  // prologue: tiles 0 and 1
  STAGE(AsB, BsB, 0);
  STAGE(AsB + 8192, BsB + 8192, 1);

  f32x4 acc[4][4];
  #pragma unroll
  for (int i = 0; i < 4; ++i)
    #pragma unroll
    for (int j = 0; j < 4; ++j) acc[i][j] = (f32x4){0.f, 0.f, 0.f, 0.f};

  const int wr = w >> 1, wc = w & 1;
  const int rA0 = wr * 64 + (l & 15);
  const int rB0 = wc * 64 + (l & 15);
  const int jk0 = (l >> 4) ^ (l & 7);        // swizzled chunk, k-half 0
  const int jk1 = ((l >> 4) + 4) ^ (l & 7);  // swizzled chunk, k-half 1

  bf16x8 pa[4], pb[4], qa[4], qb[4];

  VMWAIT(8);   // tile 0 landed (tile 1's 8 loads in flight)
  sbar();
  read_frag(AsB, BsB, rA0, rB0, jk0, pa, pb);

  for (int h = 0; h < nt; ++h) {
    const u16* Ac = AsB + (h & 1) * 8192;
    const u16* Bc = BsB + (h & 1) * 8192;
    u16* Anx = AsB + (h & 1) * 8192;
    u16* Bnx = BsB + (h & 1) * 8192;
    const u16* An1 = AsB + ((h + 1) & 1) * 8192;
    const u16* Bn1 = BsB + ((h + 1) & 1) * 8192;

    // k1 reads fly under k0 MFMA
    read_frag(Ac, Bc, rA0, rB0, jk1, qa, qb);
    mfma16x(pa, pb, acc);        // pa ready (read last iteration's tail)
    mfma16x(qa, qb, acc);        // compiler lgkmcnt gates qa/qb
    VMWAIT(0);                   // tile h+1 landed (staged one iteration ago)
    sbar();                      // block-wide: buf[h&1] free, buf[(h+1)&1] valid
    if (h + 2 < nt) STAGE(Anx, Bnx, h + 2);
    if (h + 1 < nt) read_frag(An1, Bn1, rA0, rB0, jk0, pa, pb);
  }
#undef STAGE

  // ---------------- epilogue ----------------
  const int lr0 = wr * 64 + ((l >> 4) * 4);     // local row base 0..127
  const int lc0 = wc * 64 + (l & 15);           // local col base 0..127
  const int rb = bm * 128 + lr0;
  const int cb = bn * 128 + lc0;
  #pragma unroll
  for (int mi = 0; mi < 4; ++mi) {
    const int row0 = rb + mi * 16;
    float gv[4] = {0.f, 0.f, 0.f, 0.f};
    if (MODE == 1) {
      #pragma unroll
      for (int j = 0; j < 4; ++j) gv[j] = 5.0f / (1.0f + expf(-gains[row0 + j]));
    }
    #pragma unroll
    for (int ni = 0; ni < 4; ++ni) {
      const int col = cb + ni * 16;
      f32x4 v = acc[mi][ni];
      if (MODE == 1) {
        float cpv[4];
        #pragma unroll
        for (int j = 0; j < 4; ++j) {
          float t = v[j] + orig[(size_t)(row0 + j) * N + col];
          cpv[j] = tanhf(t * gv[j]);
          C[(size_t)(row0 + j) * N + col] = cpv[j];
        }
        u16x4 o = { f2bf(cpv[0]), f2bf(cpv[1]), f2bf(cpv[2]), f2bf(cpv[3]) };
        *(u16x4*)(CbT + (size_t)col * 2048 + row0) = o;
      } else {
        #pragma unroll
        for (int j = 0; j < 4; ++j)
          C[(size_t)(row0 + j) * N + col] = v[j];
        if (MODE == 2) {
          const int lr = lr0 + mi * 16, lc = lc0 + ni * 16;
          #pragma unroll
          for (int j = 0; j < 4; ++j)
            cst[(lr + j) * 129 + lc] = v[j];
        }
      }
    }
  }
  if (MODE == 2) {
    // fused iir_partial: chunk-local scan over the 2 x 64-frame chunks of this tile
    __syncthreads();
    const int ch = tid & 127, ck2 = tid >> 7;   // channel 0..127, chunk 0..1
    const float dd = decay_of(decays[bm * 128 + ch]);
    const float* row = cst + (size_t)ch * 129 + ck2 * 64;
    float yv = 0.0f;
    #pragma unroll
    for (int i = 0; i < 64; ++i) yv = dd * (row[i] + yv);
    Lout[(bn * 2 + ck2) * 2048 + bm * 128 + ch] = yv;
  }
}

extern "C" void kernel_launch(void* const* d_in, const int* in_sizes, int n_in,
                              void* d_out, int out_size, void* d_ws, size_t ws_size,
                              hipStream_t stream) {
  const float* cp     = (const float*)d_in[0];
  const float* w1     = (const float*)d_in[1];
  const float* w2     = (const float*)d_in[2];
  const float* audio  = (const float*)d_in[3];
  const float* decays = (const float*)d_in[4];
  const float* gains  = (const float*)d_in[5];

  float* out0 = (float*)d_out;                   // audio_out: [t][w] flat
  float* out1 = out0 + (size_t)2048 * 4096;      // cp_out: [c][t]

  char* ws = (char*)d_ws;
  u16*   w1b    = (u16*)(ws);                    //  8 MB
  u16*   w2b    = (u16*)(ws + 8388608);          //  8 MB
  u16*   audiob = (u16*)(ws + 16777216);         //  8 MB
  float* orig   = (float*)(ws + 25165824);       // 32 MB
  u16*   yT     = (u16*)(ws + 58720256);         // 16 MB
  u16*   x0t    = (u16*)(ws + 75497472);         // 16 MB
  u16*   cpbT   = x0t;                           // reuse after GEMM1
  // L/Cin scratch (512 KB) lives in out0: dead until GEMM3 overwrites it all.
  float* LC     = out0;

  cvt3_kernel<<<12288, 256, 0, stream>>>(w1, w2, audio, w1b);
  relu_t_kernel<<<2048, 256, 0, stream>>>(cp, x0t);

  // x = w1 @ relu(cp) -> orig[2048][4096]; fused chunk-local IIR scan -> LC
  gemm_pl_kernel<2><<<512, 256, 0, stream>>>(w1b, x0t, orig, 4096, 2048, 2,
                                             nullptr, nullptr, nullptr, decays, LC);
  // carry scan (in-place: LC becomes Cin), then seeded apply -> yT
  iir_carry_kernel<<<16, 128, 0, stream>>>(LC, decays);
  iir_apply_kernel<<<1024, 128, 0, stream>>>(orig, decays, LC, yT);
  // x2 = w2 @ y + orig; cp_out = tanh(x2*g) -> out1 f32, cpbT[t][c] bf16
  gemm_pl_kernel<1><<<512, 256, 0, stream>>>(w2b, yT, out1, 4096, 2048, 2,
                                             orig, gains, cpbT, nullptr, nullptr);
  // audio_out[t][w] = cpbT @ audiob^T (overwrites LC scratch with final output)
  gemm_pl_kernel<0><<<512, 256, 0, stream>>>(cpbT, audiob, out0, 2048, 2048, 1,
                                             nullptr, nullptr, nullptr, nullptr, nullptr);
}